// Round 5
// baseline (247.849 us; speedup 1.0000x reference)
//
#include <hip/hip_runtime.h>

#define BB 8
#define CC 512
#define NT 4096
#define GG 8
#define CPG 64
#define EPSF 1e-6f
#define SQK 0.04419417382415922f  // 1/sqrt(512)

typedef __attribute__((ext_vector_type(8))) short bf16x8;
typedef __attribute__((ext_vector_type(4))) float f32x4;

// ws offsets (float units)
#define OFF_RED  0
#define OFF_PB2  4096
#define OFF_WKV  8192
#define OFF_PWB  270336
#define OFF_WQT  401408
#define OFF_MB   532480
#define OFF_PBF  1581056
#define OFF_CTXB 2629632
#define OFF_PCTX 3678208
#define OFF_HT   12066816
#define OFF_KVB  20455424

__device__ __forceinline__ ushort f2bf(float f) {
  union { float f; uint u; } v; v.f = f;
  uint r = (v.u + 0x7fffu + ((v.u >> 16) & 1u)) >> 16;
  return (ushort)r;
}
__device__ __forceinline__ float bf2f(ushort h) {
  union { uint u; float f; } v; v.u = ((uint)h) << 16;
  return v.f;
}
__device__ __forceinline__ uint pk(float a, float b) {
  return (uint)f2bf(a) | ((uint)f2bf(b) << 16);
}
__device__ __forceinline__ void gload16(const ushort* g, ushort* l) {
  __builtin_amdgcn_global_load_lds((const __attribute__((address_space(1))) void*)g,
                                   (__attribute__((address_space(3))) void*)l, 16, 0, 0);
}

// ---------------- GN stats: partial sums (512 blocks) ----------------
__global__ __launch_bounds__(256) void gn_stats1(const float* __restrict__ x,
                                                 float* __restrict__ red) {
  int bg = blockIdx.y, chunk = blockIdx.x;
  const float4* p4 = (const float4*)(x + (size_t)bg * (CPG * NT) + (size_t)chunk * 32768);
  int tid = threadIdx.x;
  float s = 0.f, sq = 0.f;
  for (int i = tid; i < 8192; i += 256) {
    float4 v = p4[i];
    s  += v.x + v.y + v.z + v.w;
    sq += v.x * v.x + v.y * v.y + v.z * v.z + v.w * v.w;
  }
  for (int off = 32; off > 0; off >>= 1) {
    s  += __shfl_down(s, off);
    sq += __shfl_down(sq, off);
  }
  __shared__ float ls[4], lq[4];
  int wid = tid >> 6, lane = tid & 63;
  if (lane == 0) { ls[wid] = s; lq[wid] = sq; }
  __syncthreads();
  if (tid == 0) {
    red[(bg * 8 + chunk) * 2]     = ls[0] + ls[1] + ls[2] + ls[3];
    red[(bg * 8 + chunk) * 2 + 1] = lq[0] + lq[1] + lq[2] + lq[3];
  }
}

// ---------------- weight converts: kv rows (1024) + proj_w -> bf16 ---------
__global__ __launch_bounds__(256) void wconv2(const float* __restrict__ qkv_w,
                                              const float* __restrict__ proj_w,
                                              ushort* __restrict__ wkvb,
                                              ushort* __restrict__ pwb) {
  int bid = blockIdx.x;
  if (bid < 512) {
    int idx = (bid * 256 + threadIdx.x) * 4;
    float4 v = *(const float4*)(qkv_w + (size_t)CC * CC + idx);  // k+v rows
    *(uint2*)(wkvb + idx) = make_uint2(pk(v.x, v.y), pk(v.z, v.w));
  } else {
    int idx = ((bid - 512) * 256 + threadIdx.x) * 4;
    float4 v = *(const float4*)(proj_w + idx);
    *(uint2*)(pwb + idx) = make_uint2(pk(v.x, v.y), pk(v.z, v.w));
  }
}

// ---------------- Wq^T bf16: wqT[c][d] = qkv_w[d][c] (q rows) --------------
__global__ __launch_bounds__(256) void wqt_kernel(const float* __restrict__ qkv_w,
                                                  ushort* __restrict__ wqT) {
  __shared__ float t[32][33];
  int d0 = blockIdx.y * 32, c0 = blockIdx.x * 32;
  int tid = threadIdx.x;
  int r = tid >> 3, c4 = (tid & 7) * 4;
  float4 v = *(const float4*)(qkv_w + (size_t)(d0 + r) * CC + c0 + c4);
  t[r][c4] = v.x; t[r][c4 + 1] = v.y; t[r][c4 + 2] = v.z; t[r][c4 + 3] = v.w;
  __syncthreads();
  int r2 = tid >> 3, d4 = (tid & 7) * 4;
  uint w0 = pk(t[d4][r2], t[d4 + 1][r2]);
  uint w1 = pk(t[d4 + 2][r2], t[d4 + 3][r2]);
  *(uint2*)&wqT[(size_t)(c0 + r2) * CC + d0 + d4] = make_uint2(w0, w1);
}

// ---------------- h^T in bf16 (with inline GN finalize) --------------------
__global__ __launch_bounds__(256) void ht_kernel(
    const float* __restrict__ x, const float* __restrict__ red,
    const float* __restrict__ gn_scale, const float* __restrict__ gn_bias,
    ushort* __restrict__ hT) {
  __shared__ float ts[64][68];
  __shared__ float la[64], lb[64];
  int b = blockIdx.z, g = blockIdx.y, n0 = blockIdx.x * 64;
  int c0 = g * 64;
  int tid = threadIdx.x;
  if (tid == 0) {
    int bg = b * 8 + g;
    float s = 0.f, sq = 0.f;
#pragma unroll
    for (int i = 0; i < 8; i++) {
      s  += red[(bg * 8 + i) * 2];
      sq += red[(bg * 8 + i) * 2 + 1];
    }
    float mean = s / (float)(CPG * NT);
    float var  = sq / (float)(CPG * NT) - mean * mean;
    ts[0][0] = mean; ts[0][1] = rsqrtf(var + EPSF);
  }
  __syncthreads();
  if (tid < 64) {
    float mean = ts[0][0], rstd = ts[0][1];
    float a = gn_scale[c0 + tid] * rstd;
    la[tid] = a;
    lb[tid] = gn_bias[c0 + tid] - mean * a;
  }
  __syncthreads();
  int tn = (tid & 15) * 4, tc = tid >> 4;
#pragma unroll
  for (int it = 0; it < 4; it++) {
    int c = tc + it * 16;
    float a  = la[c];
    float bb = lb[c];
    float4 v = *(const float4*)(x + ((size_t)(b * CC + c0 + c)) * NT + n0 + tn);
    ts[c][tn]     = a * v.x + bb;
    ts[c][tn + 1] = a * v.y + bb;
    ts[c][tn + 2] = a * v.z + bb;
    ts[c][tn + 3] = a * v.w + bb;
  }
  __syncthreads();
#pragma unroll
  for (int it = 0; it < 2; it++) {
    int idx = tid + it * 256;
    int n = idx >> 3, c8 = (idx & 7) * 8;
    uint w[4];
#pragma unroll
    for (int j = 0; j < 4; j++)
      w[j] = pk(ts[c8 + 2 * j][n], ts[c8 + 2 * j + 1][n]);
    *(uint4*)&hT[((size_t)b * NT + n0 + n) * CC + c0 + c8] = make_uint4(w[0], w[1], w[2], w[3]);
  }
}

// ---------------- 128x128 MFMA mainloop (A*B^T; SWAPPED operands) ----------
// mfma(b,a): C tile transposed -> lane holds row = (lane&15) on A-side,
// 4 consecutive cols (j) on B-side => packed epilogue stores.
template <int KTOT, int LDA, int LDB>
__device__ __forceinline__ void mfma_loop(const ushort* __restrict__ A,
                                          const ushort* __restrict__ B,
                                          ushort* As, ushort* Bs, int tid,
                                          f32x4 acc[4][4]) {
  int wave = tid >> 6, lane = tid & 63;
  int kofs = (lane & 3) * 8;
  int r0 = wave * 16 + (lane >> 2);
  int r1 = (wave + 4) * 16 + (lane >> 2);
  const ushort* ga0 = A + (size_t)r0 * LDA + kofs;
  const ushort* ga1 = A + (size_t)r1 * LDA + kofs;
  const ushort* gb0 = B + (size_t)r0 * LDB + kofs;
  const ushort* gb1 = B + (size_t)r1 * LDB + kofs;
  ushort* la0 = As + wave * 512;
  ushort* la1 = As + (wave + 4) * 512;
  ushort* lb0 = Bs + wave * 512;
  ushort* lb1 = Bs + (wave + 4) * 512;
  int wm = (wave >> 1) * 64, wn = (wave & 1) * 64;
  int aoff = (wm + (lane & 15)) * 32 + (lane >> 4) * 8;
  int boff = (wn + (lane & 15)) * 32 + (lane >> 4) * 8;
#pragma unroll 1
  for (int k0 = 0; k0 < KTOT; k0 += 32) {
    gload16(ga0, la0); gload16(ga1, la1);
    gload16(gb0, lb0); gload16(gb1, lb1);
    ga0 += 32; ga1 += 32; gb0 += 32; gb1 += 32;
    __syncthreads();
    bf16x8 a[4], b[4];
#pragma unroll
    for (int m = 0; m < 4; m++) a[m] = *(const bf16x8*)(As + aoff + m * 512);
#pragma unroll
    for (int n = 0; n < 4; n++) b[n] = *(const bf16x8*)(Bs + boff + n * 512);
#pragma unroll
    for (int m = 0; m < 4; m++)
#pragma unroll
      for (int n = 0; n < 4; n++)
        acc[m][n] = __builtin_amdgcn_mfma_f32_16x16x32_bf16(b[n], a[m], acc[m][n], 0, 0, 0);
    __syncthreads();
  }
}

// ---------------- 64x64 MFMA mainloop (SWAPPED operands) -------------------
template <int KTOT, int LDA, int LDB>
__device__ __forceinline__ void mfma_loop64(const ushort* __restrict__ A,
                                            const ushort* __restrict__ B,
                                            ushort* As, ushort* Bs, int tid,
                                            f32x4 acc[2][2]) {
  int wave = tid >> 6, lane = tid & 63;
  int row = tid >> 2, kofs = (tid & 3) * 8;
  const ushort* ga = A + (size_t)row * LDA + kofs;
  const ushort* gb = B + (size_t)row * LDB + kofs;
  ushort* la = As + wave * 512;
  ushort* lb = Bs + wave * 512;
  int wm = (wave >> 1) * 32, wn = (wave & 1) * 32;
  int aoff = (wm + (lane & 15)) * 32 + (lane >> 4) * 8;
  int boff = (wn + (lane & 15)) * 32 + (lane >> 4) * 8;
#pragma unroll 1
  for (int k0 = 0; k0 < KTOT; k0 += 32) {
    gload16(ga, la); gload16(gb, lb);
    ga += 32; gb += 32;
    __syncthreads();
    bf16x8 a[2], b[2];
#pragma unroll
    for (int m = 0; m < 2; m++) a[m] = *(const bf16x8*)(As + aoff + m * 512);
#pragma unroll
    for (int n = 0; n < 2; n++) b[n] = *(const bf16x8*)(Bs + boff + n * 512);
#pragma unroll
    for (int m = 0; m < 2; m++)
#pragma unroll
      for (int n = 0; n < 2; n++)
        acc[m][n] = __builtin_amdgcn_mfma_f32_16x16x32_bf16(b[n], a[m], acc[m][n], 0, 0, 0);
    __syncthreads();
  }
}

// ---------------- kv GEMM bf16: kvb[b,o,n] = sum_c Wkv[o,c] h[c,n] + bias --
__global__ __launch_bounds__(256) void kv_gemm_bf16(
    const ushort* __restrict__ wkvb, const ushort* __restrict__ hT,
    const float* __restrict__ qkv_b, ushort* __restrict__ kvb) {
  __shared__ ushort As[4096], Bs[4096];
  int b = blockIdx.z, n0 = blockIdx.x * 128, m0 = blockIdx.y * 128;
  int tid = threadIdx.x;
  f32x4 acc[4][4] = {{{0.f, 0.f, 0.f, 0.f}}};
  mfma_loop<CC, CC, CC>(wkvb + (size_t)m0 * CC,
                        hT + (size_t)b * NT * CC + (size_t)n0 * CC, As, Bs, tid, acc);
  int wave = tid >> 6, lane = tid & 63;
  int wm = (wave >> 1) * 64, wn = (wave & 1) * 64;
  int row_l = lane & 15, colq = (lane >> 4) * 4;
#pragma unroll
  for (int m = 0; m < 4; m++) {
    int gm = m0 + wm + m * 16 + row_l;
    float bias = qkv_b[CC + gm];
    ushort* orow = kvb + ((size_t)(b * 1024 + gm)) * NT + n0 + wn + colq;
#pragma unroll
    for (int n = 0; n < 4; n++) {
      uint u0 = pk(acc[m][n][0] + bias, acc[m][n][1] + bias);
      uint u1 = pk(acc[m][n][2] + bias, acc[m][n][3] + bias);
      *(uint2*)(orow + n * 16) = make_uint2(u0, u1);
    }
  }
}

// ---------------- softmax over tokens (bf16 in place, k rows) --------------
__global__ __launch_bounds__(256) void softmax_bf16(ushort* __restrict__ kvb) {
  int row = blockIdx.x;  // b*512 + d
  int b = row >> 9, d = row & 511;
  ushort* p = kvb + ((size_t)(b * 1024 + d)) * NT;
  int tid = threadIdx.x;
  uint4 r0 = *(const uint4*)(p + tid * 16);
  uint4 r1 = *(const uint4*)(p + tid * 16 + 8);
  float v[16];
  uint ws_[8] = {r0.x, r0.y, r0.z, r0.w, r1.x, r1.y, r1.z, r1.w};
#pragma unroll
  for (int i = 0; i < 8; i++) {
    union { uint u; float f; } lo, hi;
    lo.u = ws_[i] << 16; hi.u = ws_[i] & 0xffff0000u;
    v[2 * i] = lo.f; v[2 * i + 1] = hi.f;
  }
  float mx = -1e30f;
#pragma unroll
  for (int i = 0; i < 16; i++) mx = fmaxf(mx, v[i]);
  for (int off = 32; off > 0; off >>= 1) mx = fmaxf(mx, __shfl_down(mx, off));
  __shared__ float red[4];
  __shared__ float bmx, bs;
  int wid = tid >> 6, lane = tid & 63;
  if (lane == 0) red[wid] = mx;
  __syncthreads();
  if (tid == 0) bmx = fmaxf(fmaxf(red[0], red[1]), fmaxf(red[2], red[3]));
  __syncthreads();
  mx = bmx;
  float s = 0.f;
#pragma unroll
  for (int i = 0; i < 16; i++) { v[i] = expf(v[i] - mx); s += v[i]; }
  for (int off = 32; off > 0; off >>= 1) s += __shfl_down(s, off);
  __syncthreads();
  if (lane == 0) red[wid] = s;
  __syncthreads();
  if (tid == 0) bs = red[0] + red[1] + red[2] + red[3];
  __syncthreads();
  float inv = 1.f / bs;
  uint out[8];
#pragma unroll
  for (int i = 0; i < 8; i++) out[i] = pk(v[2 * i] * inv, v[2 * i + 1] * inv);
  *(uint4*)(p + tid * 16)     = make_uint4(out[0], out[1], out[2], out[3]);
  *(uint4*)(p + tid * 16 + 8) = make_uint4(out[4], out[5], out[6], out[7]);
}

// ---------------- ctx split-K: pctx[b,s,d,e] = sum_{n in split s} k v ------
__global__ __launch_bounds__(256) void ctx_gemm_split(
    const ushort* __restrict__ kvb, ushort* __restrict__ pctx) {
  __shared__ ushort As[4096], Bs[4096];
  int e0 = blockIdx.x * 128, d0 = blockIdx.y * 128;
  int bz = blockIdx.z, b = bz >> 3, s = bz & 7;
  int tid = threadIdx.x;
  f32x4 acc[4][4] = {{{0.f, 0.f, 0.f, 0.f}}};
  const ushort* K = kvb + (size_t)b * 1024 * NT + (size_t)d0 * NT + s * 512;
  const ushort* V = kvb + ((size_t)b * 1024 + 512) * NT + (size_t)e0 * NT + s * 512;
  mfma_loop<512, NT, NT>(K, V, As, Bs, tid, acc);
  int wave = tid >> 6, lane = tid & 63;
  int wm = (wave >> 1) * 64, wn = (wave & 1) * 64;
  int row_l = lane & 15, colq = (lane >> 4) * 4;
#pragma unroll
  for (int m = 0; m < 4; m++) {
    int gd = d0 + wm + m * 16 + row_l;
    ushort* orow = pctx + ((size_t)(b * 8 + s) * CC + gd) * CC + e0 + wn + colq;
#pragma unroll
    for (int n = 0; n < 4; n++) {
      uint u0 = pk(acc[m][n][0], acc[m][n][1]);
      uint u1 = pk(acc[m][n][2], acc[m][n][3]);
      *(uint2*)(orow + n * 16) = make_uint2(u0, u1);
    }
  }
}

// ---------------- reduce splits -> bf16 ctx ----------------
__global__ __launch_bounds__(256) void ctx_red(const ushort* __restrict__ pctx,
                                               ushort* __restrict__ ctxb) {
  int t = blockIdx.x * 256 + threadIdx.x;
  int b = t >> 15;
  int r = (t & 32767) * 8;
  const ushort* base = pctx + (size_t)b * 8 * 262144 + r;
  float f[8] = {};
#pragma unroll
  for (int s = 0; s < 8; s++) {
    uint4 v = *(const uint4*)(base + (size_t)s * 262144);
    uint w[4] = {v.x, v.y, v.z, v.w};
#pragma unroll
    for (int j = 0; j < 4; j++) {
      union { uint u; float f; } lo, hi;
      lo.u = w[j] << 16; hi.u = w[j] & 0xffff0000u;
      f[2 * j] += lo.f; f[2 * j + 1] += hi.f;
    }
  }
  uint o[4];
#pragma unroll
  for (int j = 0; j < 4; j++) o[j] = pk(f[2 * j], f[2 * j + 1]);
  *(uint4*)(ctxb + (size_t)b * 262144 + r) = make_uint4(o[0], o[1], o[2], o[3]);
}

// ---------------- M GEMM: Mb[b,o,d] = SQK * sum_e pw[o,e] ctx[b,d,e] -------
__global__ __launch_bounds__(256) void m_gemm_bf16(
    const ushort* __restrict__ pwb, const ushort* __restrict__ ctxb,
    ushort* __restrict__ Mb) {
  __shared__ ushort As[2048], Bs[2048];
  int b = blockIdx.z, d0 = blockIdx.x * 64, o0 = blockIdx.y * 64;
  int tid = threadIdx.x;
  f32x4 acc[2][2] = {{{0.f, 0.f, 0.f, 0.f}}};
  mfma_loop64<CC, CC, CC>(pwb + (size_t)o0 * CC,
                          ctxb + (size_t)b * CC * CC + (size_t)d0 * CC, As, Bs, tid, acc);
  int wave = tid >> 6, lane = tid & 63;
  int wm = (wave >> 1) * 32, wn = (wave & 1) * 32;
  int row_l = lane & 15, colq = (lane >> 4) * 4;
#pragma unroll
  for (int m = 0; m < 2; m++) {
    int go = o0 + wm + m * 16 + row_l;
    ushort* orow = Mb + ((size_t)b * CC + go) * CC + d0 + wn + colq;
#pragma unroll
    for (int n = 0; n < 2; n++) {
      uint u0 = pk(acc[m][n][0] * SQK, acc[m][n][1] * SQK);
      uint u1 = pk(acc[m][n][2] * SQK, acc[m][n][3] * SQK);
      *(uint2*)(orow + n * 16) = make_uint2(u0, u1);
    }
  }
}

// ---------------- P GEMM: Pb[b,o,c] = sum_d Mb[b,o,d] wqT[c,d] -------------
__global__ __launch_bounds__(256) void p_gemm_bf16(
    const ushort* __restrict__ Mb, const ushort* __restrict__ wqT,
    ushort* __restrict__ Pb) {
  __shared__ ushort As[2048], Bs[2048];
  int b = blockIdx.z, c0 = blockIdx.x * 64, o0 = blockIdx.y * 64;
  int tid = threadIdx.x;
  f32x4 acc[2][2] = {{{0.f, 0.f, 0.f, 0.f}}};
  mfma_loop64<CC, CC, CC>(Mb + (size_t)b * CC * CC + (size_t)o0 * CC,
                          wqT + (size_t)c0 * CC, As, Bs, tid, acc);
  int wave = tid >> 6, lane = tid & 63;
  int wm = (wave >> 1) * 32, wn = (wave & 1) * 32;
  int row_l = lane & 15, colq = (lane >> 4) * 4;
#pragma unroll
  for (int m = 0; m < 2; m++) {
    int go = o0 + wm + m * 16 + row_l;
    ushort* orow = Pb + ((size_t)b * CC + go) * CC + c0 + wn + colq;
#pragma unroll
    for (int n = 0; n < 2; n++) {
      uint u0 = pk(acc[m][n][0], acc[m][n][1]);
      uint u1 = pk(acc[m][n][2], acc[m][n][3]);
      *(uint2*)(orow + n * 16) = make_uint2(u0, u1);
    }
  }
}

// ---------------- pb2[b,o] = sum_d Mb[b,o,d]*bq[d] + proj_b[o] -------------
__global__ __launch_bounds__(256) void pb2_kernel(
    const ushort* __restrict__ Mb, const float* __restrict__ qkv_b,
    const float* __restrict__ proj_b, float* __restrict__ pb2) {
  int b = blockIdx.x, og = blockIdx.y;
  int r = og * 64 + (threadIdx.x >> 2);
  int q = threadIdx.x & 3;
  const ushort* Mr = Mb + ((size_t)(b * CC + r)) * CC + q * 128;
  const float* bq = qkv_b + q * 128;
  float s = 0.f;
#pragma unroll
  for (int i = 0; i < 16; i++) {
    uint4 v = *(const uint4*)(Mr + i * 8);
    uint w[4] = {v.x, v.y, v.z, v.w};
#pragma unroll
    for (int j = 0; j < 4; j++) {
      union { uint u; float f; } lo, hi;
      lo.u = w[j] << 16; hi.u = w[j] & 0xffff0000u;
      s += lo.f * bq[i * 8 + 2 * j] + hi.f * bq[i * 8 + 2 * j + 1];
    }
  }
  s += __shfl_xor(s, 1);
  s += __shfl_xor(s, 2);
  if (q == 0) pb2[b * CC + r] = s + proj_b[r];
}

// ---------------- final GEMM: out = x + P@h + pb2 (float4 epilogue) --------
__global__ __launch_bounds__(256) void final_gemm_bf16(
    const float* __restrict__ x, const ushort* __restrict__ Pb,
    const ushort* __restrict__ hT, const float* __restrict__ pb2,
    float* __restrict__ out) {
  __shared__ ushort As[4096], Bs[4096];
  int b = blockIdx.z, n0 = blockIdx.x * 128, m0 = blockIdx.y * 128;
  int tid = threadIdx.x;
  f32x4 acc[4][4] = {{{0.f, 0.f, 0.f, 0.f}}};
  mfma_loop<CC, CC, CC>(Pb + (size_t)b * CC * CC + (size_t)m0 * CC,
                        hT + (size_t)b * NT * CC + (size_t)n0 * CC, As, Bs, tid, acc);
  int wave = tid >> 6, lane = tid & 63;
  int wm = (wave >> 1) * 64, wn = (wave & 1) * 64;
  int row_l = lane & 15, colq = (lane >> 4) * 4;
#pragma unroll
  for (int m = 0; m < 4; m++) {
    int gm = m0 + wm + m * 16 + row_l;
    float bias = pb2[b * CC + gm];
    size_t rowoff = ((size_t)(b * CC + gm)) * NT + n0 + wn + colq;
#pragma unroll
    for (int n = 0; n < 4; n++) {
      float4 xr = *(const float4*)&x[rowoff + n * 16];
      float4 r;
      r.x = acc[m][n][0] + bias + xr.x;
      r.y = acc[m][n][1] + bias + xr.y;
      r.z = acc[m][n][2] + bias + xr.z;
      r.w = acc[m][n][3] + bias + xr.w;
      *(float4*)&out[rowoff + n * 16] = r;
    }
  }
}

extern "C" void kernel_launch(void* const* d_in, const int* in_sizes, int n_in,
                              void* d_out, int out_size, void* d_ws, size_t ws_size,
                              hipStream_t stream) {
  const float* x        = (const float*)d_in[0];
  const float* qkv_w    = (const float*)d_in[1];
  const float* qkv_b    = (const float*)d_in[2];
  const float* proj_w   = (const float*)d_in[3];
  const float* proj_b   = (const float*)d_in[4];
  const float* gn_scale = (const float*)d_in[5];
  const float* gn_bias  = (const float*)d_in[6];
  float* out = (float*)d_out;
  float* ws  = (float*)d_ws;

  float*  red   = ws + OFF_RED;
  float*  pb2   = ws + OFF_PB2;
  ushort* wkvb  = (ushort*)(ws + OFF_WKV);
  ushort* pwb   = (ushort*)(ws + OFF_PWB);
  ushort* wqT   = (ushort*)(ws + OFF_WQT);
  ushort* Mb    = (ushort*)(ws + OFF_MB);
  ushort* Pb    = (ushort*)(ws + OFF_PBF);
  ushort* ctxb  = (ushort*)(ws + OFF_CTXB);
  ushort* pctx  = (ushort*)(ws + OFF_PCTX);
  ushort* hT    = (ushort*)(ws + OFF_HT);
  ushort* kvb   = (ushort*)(ws + OFF_KVB);

  gn_stats1<<<dim3(8, 64), 256, 0, stream>>>(x, red);
  wconv2<<<768, 256, 0, stream>>>(qkv_w, proj_w, wkvb, pwb);
  wqt_kernel<<<dim3(16, 16), 256, 0, stream>>>(qkv_w, wqT);
  ht_kernel<<<dim3(64, 8, 8), 256, 0, stream>>>(x, red, gn_scale, gn_bias, hT);
  kv_gemm_bf16<<<dim3(32, 8, 8), 256, 0, stream>>>(wkvb, hT, qkv_b, kvb);
  softmax_bf16<<<4096, 256, 0, stream>>>(kvb);
  ctx_gemm_split<<<dim3(4, 4, 64), 256, 0, stream>>>(kvb, pctx);
  ctx_red<<<1024, 256, 0, stream>>>(pctx, ctxb);
  m_gemm_bf16<<<dim3(8, 8, 8), 256, 0, stream>>>(pwb, ctxb, Mb);
  p_gemm_bf16<<<dim3(8, 8, 8), 256, 0, stream>>>(Mb, wqT, Pb);
  pb2_kernel<<<dim3(8, 8), 256, 0, stream>>>(Mb, qkv_b, proj_b, pb2);
  final_gemm_bf16<<<dim3(32, 4, 8), 256, 0, stream>>>(x, Pb, hT, pb2, out);
}

// Round 6
// 230.366 us; speedup vs baseline: 1.0759x; 1.0759x over previous
//
#include <hip/hip_runtime.h>

#define BB 8
#define CC 512
#define NT 4096
#define GG 8
#define CPG 64
#define EPSF 1e-6f
#define SQK 0.04419417382415922f  // 1/sqrt(512)

typedef __attribute__((ext_vector_type(8))) short bf16x8;
typedef __attribute__((ext_vector_type(4))) float f32x4;

// ws offsets (float units)
#define OFF_RED  0
#define OFF_PB2  4096
#define OFF_PZ   8192
#define OFF_IZ   270336
#define OFF_WKV  274432
#define OFF_PWB  536576
#define OFF_WQT  667648
#define OFF_MB   798720
#define OFF_PBF  1847296
#define OFF_CTXB 2895872
#define OFF_PCTX 3944448
#define OFF_HT   12333056
#define OFF_KVB  20721664

__device__ __forceinline__ ushort f2bf(float f) {
  union { float f; uint u; } v; v.f = f;
  uint r = (v.u + 0x7fffu + ((v.u >> 16) & 1u)) >> 16;
  return (ushort)r;
}
__device__ __forceinline__ float bf2f(ushort h) {
  union { uint u; float f; } v; v.u = ((uint)h) << 16;
  return v.f;
}
__device__ __forceinline__ uint pk(float a, float b) {
  return (uint)f2bf(a) | ((uint)f2bf(b) << 16);
}
__device__ __forceinline__ void gload16(const ushort* g, ushort* l) {
  __builtin_amdgcn_global_load_lds((const __attribute__((address_space(1))) void*)g,
                                   (__attribute__((address_space(3))) void*)l, 16, 0, 0);
}

// ---------------- GN stats: partial sums (512 blocks) ----------------
__global__ __launch_bounds__(256) void gn_stats1(const float* __restrict__ x,
                                                 float* __restrict__ red) {
  int bg = blockIdx.y, chunk = blockIdx.x;
  const float4* p4 = (const float4*)(x + (size_t)bg * (CPG * NT) + (size_t)chunk * 32768);
  int tid = threadIdx.x;
  float s = 0.f, sq = 0.f;
  for (int i = tid; i < 8192; i += 256) {
    float4 v = p4[i];
    s  += v.x + v.y + v.z + v.w;
    sq += v.x * v.x + v.y * v.y + v.z * v.z + v.w * v.w;
  }
  for (int off = 32; off > 0; off >>= 1) {
    s  += __shfl_down(s, off);
    sq += __shfl_down(sq, off);
  }
  __shared__ float ls[4], lq[4];
  int wid = tid >> 6, lane = tid & 63;
  if (lane == 0) { ls[wid] = s; lq[wid] = sq; }
  __syncthreads();
  if (tid == 0) {
    red[(bg * 8 + chunk) * 2]     = ls[0] + ls[1] + ls[2] + ls[3];
    red[(bg * 8 + chunk) * 2 + 1] = lq[0] + lq[1] + lq[2] + lq[3];
  }
}

// ---------------- weight converts: kv rows (1024) + proj_w -> bf16 ---------
__global__ __launch_bounds__(256) void wconv2(const float* __restrict__ qkv_w,
                                              const float* __restrict__ proj_w,
                                              ushort* __restrict__ wkvb,
                                              ushort* __restrict__ pwb) {
  int bid = blockIdx.x;
  if (bid < 512) {
    int idx = (bid * 256 + threadIdx.x) * 4;
    float4 v = *(const float4*)(qkv_w + (size_t)CC * CC + idx);  // k+v rows
    *(uint2*)(wkvb + idx) = make_uint2(pk(v.x, v.y), pk(v.z, v.w));
  } else {
    int idx = ((bid - 512) * 256 + threadIdx.x) * 4;
    float4 v = *(const float4*)(proj_w + idx);
    *(uint2*)(pwb + idx) = make_uint2(pk(v.x, v.y), pk(v.z, v.w));
  }
}

// ---------------- Wq^T bf16: wqT[c][d] = qkv_w[d][c] (q rows) --------------
__global__ __launch_bounds__(256) void wqt_kernel(const float* __restrict__ qkv_w,
                                                  ushort* __restrict__ wqT) {
  __shared__ float t[32][33];
  int d0 = blockIdx.y * 32, c0 = blockIdx.x * 32;
  int tid = threadIdx.x;
  int r = tid >> 3, c4 = (tid & 7) * 4;
  float4 v = *(const float4*)(qkv_w + (size_t)(d0 + r) * CC + c0 + c4);
  t[r][c4] = v.x; t[r][c4 + 1] = v.y; t[r][c4 + 2] = v.z; t[r][c4 + 3] = v.w;
  __syncthreads();
  int r2 = tid >> 3, d4 = (tid & 7) * 4;
  uint w0 = pk(t[d4][r2], t[d4 + 1][r2]);
  uint w1 = pk(t[d4 + 2][r2], t[d4 + 3][r2]);
  *(uint2*)&wqT[(size_t)(c0 + r2) * CC + d0 + d4] = make_uint2(w0, w1);
}

// ---------------- h^T in bf16 (with inline GN finalize) --------------------
__global__ __launch_bounds__(256) void ht_kernel(
    const float* __restrict__ x, const float* __restrict__ red,
    const float* __restrict__ gn_scale, const float* __restrict__ gn_bias,
    ushort* __restrict__ hT) {
  __shared__ float ts[64][68];
  __shared__ float la[64], lb[64];
  int b = blockIdx.z, g = blockIdx.y, n0 = blockIdx.x * 64;
  int c0 = g * 64;
  int tid = threadIdx.x;
  if (tid == 0) {
    int bg = b * 8 + g;
    float s = 0.f, sq = 0.f;
#pragma unroll
    for (int i = 0; i < 8; i++) {
      s  += red[(bg * 8 + i) * 2];
      sq += red[(bg * 8 + i) * 2 + 1];
    }
    float mean = s / (float)(CPG * NT);
    float var  = sq / (float)(CPG * NT) - mean * mean;
    ts[0][0] = mean; ts[0][1] = rsqrtf(var + EPSF);
  }
  __syncthreads();
  if (tid < 64) {
    float mean = ts[0][0], rstd = ts[0][1];
    float a = gn_scale[c0 + tid] * rstd;
    la[tid] = a;
    lb[tid] = gn_bias[c0 + tid] - mean * a;
  }
  __syncthreads();
  int tn = (tid & 15) * 4, tc = tid >> 4;
#pragma unroll
  for (int it = 0; it < 4; it++) {
    int c = tc + it * 16;
    float a  = la[c];
    float bb = lb[c];
    float4 v = *(const float4*)(x + ((size_t)(b * CC + c0 + c)) * NT + n0 + tn);
    ts[c][tn]     = a * v.x + bb;
    ts[c][tn + 1] = a * v.y + bb;
    ts[c][tn + 2] = a * v.z + bb;
    ts[c][tn + 3] = a * v.w + bb;
  }
  __syncthreads();
#pragma unroll
  for (int it = 0; it < 2; it++) {
    int idx = tid + it * 256;
    int n = idx >> 3, c8 = (idx & 7) * 8;
    uint w[4];
#pragma unroll
    for (int j = 0; j < 4; j++)
      w[j] = pk(ts[c8 + 2 * j][n], ts[c8 + 2 * j + 1][n]);
    *(uint4*)&hT[((size_t)b * NT + n0 + n) * CC + c0 + c8] = make_uint4(w[0], w[1], w[2], w[3]);
  }
}

// ------- 128x128 MFMA mainloop, 2-phase double-buffered (A*B^T) ------------
// As/Bs are 8192 ushorts each (2 x 4096 buffers).
template <int KTOT, int LDA, int LDB>
__device__ __forceinline__ void mfma_loop(const ushort* __restrict__ A,
                                          const ushort* __restrict__ B,
                                          ushort* As, ushort* Bs, int tid,
                                          f32x4 acc[4][4]) {
  int wave = tid >> 6, lane = tid & 63;
  int kofs = (lane & 3) * 8;
  int r0 = wave * 16 + (lane >> 2);
  int r1 = (wave + 4) * 16 + (lane >> 2);
  const ushort* ga0 = A + (size_t)r0 * LDA + kofs;
  const ushort* ga1 = A + (size_t)r1 * LDA + kofs;
  const ushort* gb0 = B + (size_t)r0 * LDB + kofs;
  const ushort* gb1 = B + (size_t)r1 * LDB + kofs;
  int lo0 = wave * 512, lo1 = (wave + 4) * 512;
  int wm = (wave >> 1) * 64, wn = (wave & 1) * 64;
  int aoff = (wm + (lane & 15)) * 32 + (lane >> 4) * 8;
  int boff = (wn + (lane & 15)) * 32 + (lane >> 4) * 8;
  constexpr int NIT = KTOT / 32;
  // prologue: stage tile 0 into buffer 0
  gload16(ga0, As + lo0); gload16(ga1, As + lo1);
  gload16(gb0, Bs + lo0); gload16(gb1, Bs + lo1);
  ga0 += 32; ga1 += 32; gb0 += 32; gb1 += 32;
  __syncthreads();
#pragma unroll 1
  for (int t = 0; t < NIT; t++) {
    int cb = (t & 1) * 4096;
    int nb = 4096 - cb;
    if (t + 1 < NIT) {  // stage next tile into alternate buffer (overlaps compute)
      gload16(ga0, As + nb + lo0); gload16(ga1, As + nb + lo1);
      gload16(gb0, Bs + nb + lo0); gload16(gb1, Bs + nb + lo1);
      ga0 += 32; ga1 += 32; gb0 += 32; gb1 += 32;
    }
    bf16x8 a[4], b[4];
#pragma unroll
    for (int m = 0; m < 4; m++) a[m] = *(const bf16x8*)(As + cb + aoff + m * 512);
#pragma unroll
    for (int n = 0; n < 4; n++) b[n] = *(const bf16x8*)(Bs + cb + boff + n * 512);
#pragma unroll
    for (int m = 0; m < 4; m++)
#pragma unroll
      for (int n = 0; n < 4; n++)
        acc[m][n] = __builtin_amdgcn_mfma_f32_16x16x32_bf16(a[m], b[n], acc[m][n], 0, 0, 0);
    __syncthreads();  // drains staged loads; next iter reads alternate buffer
  }
}

// ------- 64x64 MFMA mainloop, 2-phase double-buffered ----------------------
// As/Bs are 4096 ushorts each (2 x 2048 buffers).
template <int KTOT, int LDA, int LDB>
__device__ __forceinline__ void mfma_loop64(const ushort* __restrict__ A,
                                            const ushort* __restrict__ B,
                                            ushort* As, ushort* Bs, int tid,
                                            f32x4 acc[2][2]) {
  int wave = tid >> 6, lane = tid & 63;
  int row = tid >> 2, kofs = (tid & 3) * 8;
  const ushort* ga = A + (size_t)row * LDA + kofs;
  const ushort* gb = B + (size_t)row * LDB + kofs;
  int lo = wave * 512;
  int wm = (wave >> 1) * 32, wn = (wave & 1) * 32;
  int aoff = (wm + (lane & 15)) * 32 + (lane >> 4) * 8;
  int boff = (wn + (lane & 15)) * 32 + (lane >> 4) * 8;
  constexpr int NIT = KTOT / 32;
  gload16(ga, As + lo); gload16(gb, Bs + lo);
  ga += 32; gb += 32;
  __syncthreads();
#pragma unroll 1
  for (int t = 0; t < NIT; t++) {
    int cb = (t & 1) * 2048;
    int nb = 2048 - cb;
    if (t + 1 < NIT) {
      gload16(ga, As + nb + lo); gload16(gb, Bs + nb + lo);
      ga += 32; gb += 32;
    }
    bf16x8 a[2], b[2];
#pragma unroll
    for (int m = 0; m < 2; m++) a[m] = *(const bf16x8*)(As + cb + aoff + m * 512);
#pragma unroll
    for (int n = 0; n < 2; n++) b[n] = *(const bf16x8*)(Bs + cb + boff + n * 512);
#pragma unroll
    for (int m = 0; m < 2; m++)
#pragma unroll
      for (int n = 0; n < 2; n++)
        acc[m][n] = __builtin_amdgcn_mfma_f32_16x16x32_bf16(a[m], b[n], acc[m][n], 0, 0, 0);
    __syncthreads();
  }
}

// --- kv GEMM bf16 + fused exp on k-rows + partial row-sums pZ --------------
// kvb[b,o,n] = (o<512 ? exp(k) : v) where k/v = sum_c Wkv[o,c] h[c,n] + bias
__global__ __launch_bounds__(256) void kv_gemm_bf16(
    const ushort* __restrict__ wkvb, const ushort* __restrict__ hT,
    const float* __restrict__ qkv_b, ushort* __restrict__ kvb,
    float* __restrict__ pZ) {
  __shared__ ushort As[8192], Bs[8192];
  int b = blockIdx.z, n0 = blockIdx.x * 128, m0 = blockIdx.y * 128;
  int tid = threadIdx.x;
  f32x4 acc[4][4] = {{{0.f, 0.f, 0.f, 0.f}}};
  mfma_loop<CC, CC, CC>(wkvb + (size_t)m0 * CC,
                        hT + (size_t)b * NT * CC + (size_t)n0 * CC, As, Bs, tid, acc);
  int wave = tid >> 6, lane = tid & 63;
  int wm = (wave >> 1) * 64, wn = (wave & 1) * 64;
  int col = lane & 15, rb = (lane >> 4) * 4;
  if (m0 < 512) {
    // k rows: raw exp (softmax is shift-invariant; |k|<~6 so no overflow)
    int chunk = (n0 >> 6) + (wave & 1);
#pragma unroll
    for (int m = 0; m < 4; m++)
#pragma unroll
      for (int j = 0; j < 4; j++) {
        int gm = m0 + wm + m * 16 + rb + j;
        float bias = qkv_b[CC + gm];
        float zs = 0.f;
#pragma unroll
        for (int n = 0; n < 4; n++) {
          float e = expf(acc[m][n][j] + bias);
          zs += e;
          int gn = n0 + wn + n * 16 + col;
          kvb[((size_t)(b * 1024 + gm)) * NT + gn] = f2bf(e);
        }
        zs += __shfl_xor(zs, 1); zs += __shfl_xor(zs, 2);
        zs += __shfl_xor(zs, 4); zs += __shfl_xor(zs, 8);
        if (col == 0) pZ[((size_t)(b * 512 + gm)) * 64 + chunk] = zs;
      }
  } else {
#pragma unroll
    for (int m = 0; m < 4; m++)
#pragma unroll
      for (int n = 0; n < 4; n++)
#pragma unroll
        for (int j = 0; j < 4; j++) {
          int gm = m0 + wm + m * 16 + rb + j;
          int gn = n0 + wn + n * 16 + col;
          kvb[((size_t)(b * 1024 + gm)) * NT + gn] = f2bf(acc[m][n][j] + qkv_b[CC + gm]);
        }
  }
}

// ---------------- invZ[b*512+d] = 1 / sum_chunks pZ ------------------------
__global__ __launch_bounds__(256) void zred(const float* __restrict__ pZ,
                                            float* __restrict__ invZ) {
  int t = blockIdx.x * 256 + threadIdx.x;  // 4096
  const float4* p = (const float4*)(pZ + (size_t)t * 64);
  float s = 0.f;
#pragma unroll
  for (int i = 0; i < 16; i++) { float4 v = p[i]; s += v.x + v.y + v.z + v.w; }
  invZ[t] = 1.f / s;
}

// ---------------- ctx split-K: pctx[b,s,d,e] = sum_{n in split s} ek v -----
__global__ __launch_bounds__(256) void ctx_gemm_split(
    const ushort* __restrict__ kvb, ushort* __restrict__ pctx) {
  __shared__ ushort As[8192], Bs[8192];
  int e0 = blockIdx.x * 128, d0 = blockIdx.y * 128;
  int bz = blockIdx.z, b = bz >> 3, s = bz & 7;
  int tid = threadIdx.x;
  f32x4 acc[4][4] = {{{0.f, 0.f, 0.f, 0.f}}};
  const ushort* K = kvb + (size_t)b * 1024 * NT + (size_t)d0 * NT + s * 512;
  const ushort* V = kvb + ((size_t)b * 1024 + 512) * NT + (size_t)e0 * NT + s * 512;
  mfma_loop<512, NT, NT>(K, V, As, Bs, tid, acc);
  int wave = tid >> 6, lane = tid & 63;
  int wm = (wave >> 1) * 64, wn = (wave & 1) * 64;
  int col = lane & 15, rb = (lane >> 4) * 4;
#pragma unroll
  for (int m = 0; m < 4; m++)
#pragma unroll
    for (int n = 0; n < 4; n++)
#pragma unroll
      for (int j = 0; j < 4; j++) {
        int gd = d0 + wm + m * 16 + rb + j;
        int ge = e0 + wn + n * 16 + col;
        pctx[((size_t)(b * 8 + s) * CC + gd) * CC + ge] = f2bf(acc[m][n][j]);
      }
}

// ---------------- reduce splits + row-normalize -> bf16 ctx ----------------
__global__ __launch_bounds__(256) void ctx_red(const ushort* __restrict__ pctx,
                                               const float* __restrict__ invZ,
                                               ushort* __restrict__ ctxb) {
  int t = blockIdx.x * 256 + threadIdx.x;
  int b = t >> 15;
  int r = (t & 32767) * 8;
  int d = r >> 9;
  float iz = invZ[b * 512 + d];
  const ushort* base = pctx + (size_t)b * 8 * 262144 + r;
  float f[8] = {};
#pragma unroll
  for (int s = 0; s < 8; s++) {
    uint4 v = *(const uint4*)(base + (size_t)s * 262144);
    uint w[4] = {v.x, v.y, v.z, v.w};
#pragma unroll
    for (int j = 0; j < 4; j++) {
      union { uint u; float f; } lo, hi;
      lo.u = w[j] << 16; hi.u = w[j] & 0xffff0000u;
      f[2 * j] += lo.f; f[2 * j + 1] += hi.f;
    }
  }
  uint o[4];
#pragma unroll
  for (int j = 0; j < 4; j++) o[j] = pk(f[2 * j] * iz, f[2 * j + 1] * iz);
  *(uint4*)(ctxb + (size_t)b * 262144 + r) = make_uint4(o[0], o[1], o[2], o[3]);
}

// ---------------- M GEMM: Mb[b,o,d] = SQK * sum_e pw[o,e] ctx[b,d,e] -------
__global__ __launch_bounds__(256) void m_gemm_bf16(
    const ushort* __restrict__ pwb, const ushort* __restrict__ ctxb,
    ushort* __restrict__ Mb) {
  __shared__ ushort As[4096], Bs[4096];
  int b = blockIdx.z, d0 = blockIdx.x * 64, o0 = blockIdx.y * 64;
  int tid = threadIdx.x;
  f32x4 acc[2][2] = {{{0.f, 0.f, 0.f, 0.f}}};
  mfma_loop64<CC, CC, CC>(pwb + (size_t)o0 * CC,
                          ctxb + (size_t)b * CC * CC + (size_t)d0 * CC, As, Bs, tid, acc);
  int wave = tid >> 6, lane = tid & 63;
  int wm = (wave >> 1) * 32, wn = (wave & 1) * 32;
  int col = lane & 15, rb = (lane >> 4) * 4;
#pragma unroll
  for (int m = 0; m < 2; m++)
#pragma unroll
    for (int n = 0; n < 2; n++)
#pragma unroll
      for (int j = 0; j < 4; j++) {
        int go = o0 + wm + m * 16 + rb + j;
        int gd = d0 + wn + n * 16 + col;
        Mb[((size_t)b * CC + go) * CC + gd] = f2bf(acc[m][n][j] * SQK);
      }
}

// ---------------- P GEMM: Pb[b,o,c] = sum_d Mb[b,o,d] wqT[c,d] -------------
__global__ __launch_bounds__(256) void p_gemm_bf16(
    const ushort* __restrict__ Mb, const ushort* __restrict__ wqT,
    ushort* __restrict__ Pb) {
  __shared__ ushort As[4096], Bs[4096];
  int b = blockIdx.z, c0 = blockIdx.x * 64, o0 = blockIdx.y * 64;
  int tid = threadIdx.x;
  f32x4 acc[2][2] = {{{0.f, 0.f, 0.f, 0.f}}};
  mfma_loop64<CC, CC, CC>(Mb + (size_t)b * CC * CC + (size_t)o0 * CC,
                          wqT + (size_t)c0 * CC, As, Bs, tid, acc);
  int wave = tid >> 6, lane = tid & 63;
  int wm = (wave >> 1) * 32, wn = (wave & 1) * 32;
  int col = lane & 15, rb = (lane >> 4) * 4;
#pragma unroll
  for (int m = 0; m < 2; m++)
#pragma unroll
    for (int n = 0; n < 2; n++)
#pragma unroll
      for (int j = 0; j < 4; j++) {
        int go = o0 + wm + m * 16 + rb + j;
        int gc = c0 + wn + n * 16 + col;
        Pb[((size_t)b * CC + go) * CC + gc] = f2bf(acc[m][n][j]);
      }
}

// ---------------- pb2[b,o] = sum_d Mb[b,o,d]*bq[d] + proj_b[o] -------------
__global__ __launch_bounds__(256) void pb2_kernel(
    const ushort* __restrict__ Mb, const float* __restrict__ qkv_b,
    const float* __restrict__ proj_b, float* __restrict__ pb2) {
  int b = blockIdx.x, og = blockIdx.y;
  int r = og * 64 + (threadIdx.x >> 2);
  int q = threadIdx.x & 3;
  const ushort* Mr = Mb + ((size_t)(b * CC + r)) * CC + q * 128;
  const float* bq = qkv_b + q * 128;
  float s = 0.f;
#pragma unroll
  for (int i = 0; i < 16; i++) {
    uint4 v = *(const uint4*)(Mr + i * 8);
    uint w[4] = {v.x, v.y, v.z, v.w};
#pragma unroll
    for (int j = 0; j < 4; j++) {
      union { uint u; float f; } lo, hi;
      lo.u = w[j] << 16; hi.u = w[j] & 0xffff0000u;
      s += lo.f * bq[i * 8 + 2 * j] + hi.f * bq[i * 8 + 2 * j + 1];
    }
  }
  s += __shfl_xor(s, 1);
  s += __shfl_xor(s, 2);
  if (q == 0) pb2[b * CC + r] = s + proj_b[r];
}

// ---------------- final GEMM: out = x + P@h + pb2 --------------------------
__global__ __launch_bounds__(256) void final_gemm_bf16(
    const float* __restrict__ x, const ushort* __restrict__ Pb,
    const ushort* __restrict__ hT, const float* __restrict__ pb2,
    float* __restrict__ out) {
  __shared__ ushort As[8192], Bs[8192];
  int b = blockIdx.z, n0 = blockIdx.x * 128, m0 = blockIdx.y * 128;
  int tid = threadIdx.x;
  f32x4 acc[4][4] = {{{0.f, 0.f, 0.f, 0.f}}};
  mfma_loop<CC, CC, CC>(Pb + (size_t)b * CC * CC + (size_t)m0 * CC,
                        hT + (size_t)b * NT * CC + (size_t)n0 * CC, As, Bs, tid, acc);
  int wave = tid >> 6, lane = tid & 63;
  int wm = (wave >> 1) * 64, wn = (wave & 1) * 64;
  int col = lane & 15, rb = (lane >> 4) * 4;
#pragma unroll
  for (int m = 0; m < 4; m++)
#pragma unroll
    for (int n = 0; n < 4; n++)
#pragma unroll
      for (int j = 0; j < 4; j++) {
        int gm = m0 + wm + m * 16 + rb + j;
        int gn = n0 + wn + n * 16 + col;
        size_t idx = ((size_t)(b * CC + gm)) * NT + gn;
        out[idx] = acc[m][n][j] + pb2[b * CC + gm] + x[idx];
      }
}

extern "C" void kernel_launch(void* const* d_in, const int* in_sizes, int n_in,
                              void* d_out, int out_size, void* d_ws, size_t ws_size,
                              hipStream_t stream) {
  const float* x        = (const float*)d_in[0];
  const float* qkv_w    = (const float*)d_in[1];
  const float* qkv_b    = (const float*)d_in[2];
  const float* proj_w   = (const float*)d_in[3];
  const float* proj_b   = (const float*)d_in[4];
  const float* gn_scale = (const float*)d_in[5];
  const float* gn_bias  = (const float*)d_in[6];
  float* out = (float*)d_out;
  float* ws  = (float*)d_ws;

  float*  red   = ws + OFF_RED;
  float*  pb2   = ws + OFF_PB2;
  float*  pZ    = ws + OFF_PZ;
  float*  invZ  = ws + OFF_IZ;
  ushort* wkvb  = (ushort*)(ws + OFF_WKV);
  ushort* pwb   = (ushort*)(ws + OFF_PWB);
  ushort* wqT   = (ushort*)(ws + OFF_WQT);
  ushort* Mb    = (ushort*)(ws + OFF_MB);
  ushort* Pb    = (ushort*)(ws + OFF_PBF);
  ushort* ctxb  = (ushort*)(ws + OFF_CTXB);
  ushort* pctx  = (ushort*)(ws + OFF_PCTX);
  ushort* hT    = (ushort*)(ws + OFF_HT);
  ushort* kvb   = (ushort*)(ws + OFF_KVB);

  gn_stats1<<<dim3(8, 64), 256, 0, stream>>>(x, red);
  wconv2<<<768, 256, 0, stream>>>(qkv_w, proj_w, wkvb, pwb);
  wqt_kernel<<<dim3(16, 16), 256, 0, stream>>>(qkv_w, wqT);
  ht_kernel<<<dim3(64, 8, 8), 256, 0, stream>>>(x, red, gn_scale, gn_bias, hT);
  kv_gemm_bf16<<<dim3(32, 8, 8), 256, 0, stream>>>(wkvb, hT, qkv_b, kvb, pZ);
  zred<<<16, 256, 0, stream>>>(pZ, invZ);
  ctx_gemm_split<<<dim3(4, 4, 64), 256, 0, stream>>>(kvb, pctx);
  ctx_red<<<1024, 256, 0, stream>>>(pctx, invZ, ctxb);
  m_gemm_bf16<<<dim3(8, 8, 8), 256, 0, stream>>>(pwb, ctxb, Mb);
  p_gemm_bf16<<<dim3(8, 8, 8), 256, 0, stream>>>(Mb, wqT, Pb);
  pb2_kernel<<<dim3(8, 8), 256, 0, stream>>>(Mb, qkv_b, proj_b, pb2);
  final_gemm_bf16<<<dim3(32, 4, 8), 256, 0, stream>>>(x, Pb, hT, pb2, out);
}